// Round 6
// baseline (25819.806 us; speedup 1.0000x reference)
//
#include <hip/hip_runtime.h>
#include <stdint.h>

// LSTM classifier: VOCAB=32000, H=512, LAYERS=2, LABELS=4, B=32, T=2048
#define TSEQ 2048
#define BATCH 32
#define HID 512
#define NWGL 16          // WGs per layer; each owns 32 hidden units (128 gate rows)
#define NWG_ALL 32

typedef _Float16 half8 __attribute__((ext_vector_type(8)));
typedef float floatx4 __attribute__((ext_vector_type(4)));

__device__ __forceinline__ float sigf(float x){ return 1.f/(1.f+__expf(-x)); }
__device__ __forceinline__ float tanh_(float x){
  float e = __expf(-2.f*fabsf(x));
  float r = (1.f-e)/(1.f+e);
  return x<0.f ? -r : r;
}
__device__ __forceinline__ half8 cvt8(float4 a, float4 b){
  return half8{(_Float16)a.x,(_Float16)a.y,(_Float16)a.z,(_Float16)a.w,
               (_Float16)b.x,(_Float16)b.y,(_Float16)b.z,(_Float16)b.w};
}
// device-coherent 16B load (2x8B sc0 sc1 -> MALL; coalesced with transposed layout)
__device__ __forceinline__ half8 ldh8_coh(const _Float16* p){
  const unsigned long long* q = (const unsigned long long*)p;
  unsigned long long a = __hip_atomic_load(q,   __ATOMIC_RELAXED, __HIP_MEMORY_SCOPE_AGENT);
  unsigned long long b = __hip_atomic_load(q+1, __ATOMIC_RELAXED, __HIP_MEMORY_SCOPE_AGENT);
  union { unsigned long long u[2]; half8 h; } v; v.u[0]=a; v.u[1]=b; return v.h;
}

// ---------------- emb f32 -> f16 (flat convert)
__global__ void k_cvt_emb(const float* __restrict__ in, _Float16* __restrict__ out, int n8){
  int i = blockIdx.x*256 + threadIdx.x;
  if (i < n8){
    const float4* s = (const float4*)(in + (size_t)i*8);
    *(half8*)(out + (size_t)i*8) = cvt8(s[0], s[1]);
  }
}

// ---------------- fused 2-layer persistent LSTM.
// 16 WGs/layer x 512 threads (8 waves). Wave w: A-tile rows m_local=w*16+r15 of
// the WG's 128 gate rows; remap grow = (m&3)*512 + wg*32 + (m>>2) so C-frag
// regs r=0..3 of thread (w,kg,r15) are gates i,f,g,o of unit u=w*4+kg for
// batches r15 and 16+r15 (two N-tiles). Weights live in VGPRs (wx/wh 128 regs).
// h exchange: MALL-coherent ring, CHUNK-TRANSPOSED [slot][k>>3][batch][8] so
// B-frag loads are lane-consecutive (coalesced). Layer 1 runs at skew 2.
__global__ void __launch_bounds__(512,1) k_main(
    const int* __restrict__ xtok, const _Float16* __restrict__ emb16,
    const float* __restrict__ Wih, const float* __restrict__ Whh,
    const float* __restrict__ bih, const float* __restrict__ bhh,
    _Float16* __restrict__ h0ring, _Float16* __restrict__ h1ring,
    float* __restrict__ hT, unsigned* __restrict__ flags){
  int tid = threadIdx.x, lane = tid&63, wave = tid>>6;   // wave 0..7
  int wgAll = blockIdx.x, layer = wgAll>>4, wg = wgAll&15;
  int kg = lane>>4, r15 = lane&15;

  // ---- one-time: weight A-fragments into registers (f32 -> f16)
  half8 wx[16], wh[16];
  {
    int m = wave*16 + r15;                         // row in WG's 128-row tile
    int grow = ((m&3)<<9) + (wg<<5) + (m>>2);
    const float* pwx = Wih + ((size_t)layer*2048 + grow)*HID + kg*8;
    const float* pwh = Whh + ((size_t)layer*2048 + grow)*HID + kg*8;
    #pragma unroll
    for (int ks=0; ks<16; ++ks){
      wx[ks] = cvt8(*(const float4*)(pwx + ks*32), *(const float4*)(pwx + ks*32 + 4));
      wh[ks] = cvt8(*(const float4*)(pwh + ks*32), *(const float4*)(pwh + ks*32 + 4));
    }
  }
  int u = wave*4 + kg;                // owned unit within WG (0..31)
  int j = (wg<<5) + u;                // global hidden unit (0..511)
  float bias[4];
  #pragma unroll
  for (int r=0; r<4; ++r){
    int g = layer*2048 + (r<<9) + (wg<<5) + u;
    bias[r] = bih[g] + bhh[g];
  }

  unsigned* ring32 = (unsigned*)(layer ? h1ring : h0ring);
  const _Float16* hring = layer ? h1ring : h0ring;
  // transposed slot layout: element(j,b) at ((j>>3)*32 + b)*8 + (j&7); slot = 16384 el
  int stElemBase = ((j>>3)*32)*8 + (j&7);          // + b*8 later

  // ---- prologue: layer-0 x-projection for t=0
  floatx4 accx0 = {bias[0],bias[1],bias[2],bias[3]};
  floatx4 accx1 = accx0;
  if (layer == 0){
    #pragma unroll
    for (int nt=0; nt<2; ++nt){
      int tok = xtok[(nt*16+r15)*TSEQ + 0];
      const _Float16* px = emb16 + (size_t)tok*HID + kg*8;
      floatx4 a = nt ? accx1 : accx0;
      #pragma unroll
      for (int ks=0; ks<16; ++ks){
        half8 xf = *(const half8*)(px + ks*32);
        a = __builtin_amdgcn_mfma_f32_16x16x32_f16(wx[ks], xf, a, 0,0,0);
      }
      if (nt) accx1 = a; else accx0 = a;
    }
  }

  float c0 = 0.f, c1 = 0.f;
  for (int tt=0; tt<=TSEQ+1; ++tt){
    bool act = (layer==0) ? (tt < TSEQ) : (tt >= 2);
    int t = (layer==0) ? tt : tt-2;
    if (act){
      floatx4 acc0 = accx0, acc1 = accx1;
      if (t > 0){
        const _Float16* hb = hring + (size_t)((t-1)&7)*(BATCH*HID);
        #pragma unroll
        for (int nt=0; nt<2; ++nt){
          half8 hf[16];
          #pragma unroll
          for (int ks=0; ks<16; ++ks)
            hf[ks] = ldh8_coh(hb + (((ks*4+kg)*32 + nt*16 + r15)<<3));
          floatx4 a = nt ? acc1 : acc0;
          #pragma unroll
          for (int ks=0; ks<16; ++ks)
            a = __builtin_amdgcn_mfma_f32_16x16x32_f16(wh[ks], hf[ks], a, 0,0,0);
          if (nt) acc1 = a; else acc0 = a;
        }
      }
      // in-register cell update (gates i,f,g,o = regs 0..3), two batches
      c0 = sigf(acc0[1])*c0 + sigf(acc0[0])*tanh_(acc0[2]);
      float h0v = sigf(acc0[3])*tanh_(c0);
      c1 = sigf(acc1[1])*c1 + sigf(acc1[0])*tanh_(acc1[2]);
      float h1v = sigf(acc1[3])*tanh_(c1);
      // pack (j, j+1) pair -> one coherent dword store (even-kg lanes)
      size_t slotBase = (size_t)(t&7)*(BATCH*HID);
      unsigned b0, b1;
      { _Float16 hh = (_Float16)h0v; unsigned short s; __builtin_memcpy(&s,&hh,2); b0 = s; }
      { _Float16 hh = (_Float16)h1v; unsigned short s; __builtin_memcpy(&s,&hh,2); b1 = s; }
      unsigned p0 = __shfl_down(b0, 16), p1 = __shfl_down(b1, 16);
      if ((kg & 1) == 0){
        __hip_atomic_store(&ring32[(slotBase + stElemBase + (size_t)(r15)*8)>>1],
                           b0 | (p0<<16), __ATOMIC_RELAXED, __HIP_MEMORY_SCOPE_AGENT);
        __hip_atomic_store(&ring32[(slotBase + stElemBase + (size_t)(16+r15)*8)>>1],
                           b1 | (p1<<16), __ATOMIC_RELAXED, __HIP_MEMORY_SCOPE_AGENT);
      }
      if (layer==1 && t==TSEQ-1){
        hT[(r15)*HID + j] = h0v;
        hT[(16+r15)*HID + j] = h1v;
      }
    }
    __syncthreads();                  // all waves vmcnt(0): h stores MALL-acked
    if (tid == 0)
      __hip_atomic_store(&flags[wgAll], (unsigned)(tt+1),
                         __ATOMIC_RELAXED, __HIP_MEMORY_SCOPE_AGENT);
    // ---- prefetch next tick's x-projection (under the barrier wait)
    int ntt = tt+1;
    bool nact = (layer==0) ? (ntt < TSEQ) : (ntt >= 2 && ntt <= TSEQ+1);
    if (nact){
      accx0 = floatx4{bias[0],bias[1],bias[2],bias[3]};
      accx1 = accx0;
      #pragma unroll
      for (int nt=0; nt<2; ++nt){
        half8 xf[16];
        if (layer == 0){
          int tok = xtok[(nt*16+r15)*TSEQ + ntt];
          const _Float16* px = emb16 + (size_t)tok*HID + kg*8;
          #pragma unroll
          for (int ks=0; ks<16; ++ks) xf[ks] = *(const half8*)(px + ks*32);
        } else {
          const _Float16* px = h0ring + (size_t)((ntt-2)&7)*(BATCH*HID);
          #pragma unroll
          for (int ks=0; ks<16; ++ks)
            xf[ks] = ldh8_coh(px + (((ks*4+kg)*32 + nt*16 + r15)<<3));
        }
        floatx4 a = nt ? accx1 : accx0;
        #pragma unroll
        for (int ks=0; ks<16; ++ks)
          a = __builtin_amdgcn_mfma_f32_16x16x32_f16(wx[ks], xf[ks], a, 0,0,0);
        if (nt) accx1 = a; else accx0 = a;
      }
    }
    // ---- flag barrier: every wave polls the 32 flags independently
    if (tt <= TSEQ){
      unsigned tgt = (unsigned)(tt+1);
      for (;;){
        unsigned f = tgt;
        if (lane < NWG_ALL)
          f = __hip_atomic_load(&flags[lane], __ATOMIC_RELAXED, __HIP_MEMORY_SCOPE_AGENT);
        if (__all(f >= tgt)) break;
        __builtin_amdgcn_s_sleep(2);
      }
    }
  }
}

// ---------------- classifier + log_softmax + NLL loss
__global__ void k_cls(const float* __restrict__ hT, const float* __restrict__ fcw,
                      const float* __restrict__ fcb, const int* __restrict__ labels,
                      float* __restrict__ out){
  __shared__ float lg[128];
  __shared__ float ls[32];
  int tid = threadIdx.x;
  if (tid < 128){
    int b = tid>>2, n = tid&3;
    const float4* hp = (const float4*)(hT + b*HID);
    const float4* wp = (const float4*)(fcw + n*HID);
    float s = 0.f;
    for (int k=0;k<128;++k){ float4 a = hp[k], w = wp[k];
      s += a.x*w.x + a.y*w.y + a.z*w.z + a.w*w.w; }
    lg[tid] = s + fcb[n];
  }
  __syncthreads();
  if (tid < 32){
    float x0 = lg[tid*4+0], x1 = lg[tid*4+1], x2 = lg[tid*4+2], x3 = lg[tid*4+3];
    float mx = fmaxf(fmaxf(x0,x1),fmaxf(x2,x3));
    float lse = mx + logf(__expf(x0-mx)+__expf(x1-mx)+__expf(x2-mx)+__expf(x3-mx));
    ls[tid] = lse - lg[tid*4 + labels[tid]];
  }
  __syncthreads();
  if (tid == 0){
    float s = 0.f;
    for (int b=0;b<32;++b) s += ls[b];
    out[0] = s * (1.f/32.f);
  }
  if (tid < 128) out[1+tid] = lg[tid];
}

extern "C" void kernel_launch(void* const* d_in, const int* in_sizes, int n_in,
                              void* d_out, int out_size, void* d_ws, size_t ws_size,
                              hipStream_t stream) {
  const int*   x      = (const int*)d_in[0];
  const int*   labels = (const int*)d_in[1];
  const float* emb    = (const float*)d_in[2];
  const float* Wih    = (const float*)d_in[3];
  const float* Whh    = (const float*)d_in[4];
  const float* bih    = (const float*)d_in[5];
  const float* bhh    = (const float*)d_in[6];
  const float* fcw    = (const float*)d_in[7];
  const float* fcb    = (const float*)d_in[8];
  float* out = (float*)d_out;
  char* ws = (char*)d_ws;

  _Float16* emb16  = (_Float16*)(ws);                            // 31.25MB
  _Float16* h0ring = (_Float16*)(ws + (32ull<<20));              // 256KB (8 slots)
  _Float16* h1ring = (_Float16*)(ws + (32ull<<20) + (256<<10));  // 256KB
  float*    hT     = (float*)   (ws + (32ull<<20) + (512<<10));  // 64KB
  unsigned* flags  = (unsigned*)(ws + (32ull<<20) + (576<<10));  // 128B

  hipMemsetAsync(flags, 0, 1024, stream);
  k_cvt_emb<<<8000, 256, 0, stream>>>(emb, emb16, 2048000);
  k_main<<<NWG_ALL, 512, 0, stream>>>(x, emb16, Wih, Whh, bih, bhh,
                                      h0ring, h1ring, hT, flags);
  k_cls<<<1, 256, 0, stream>>>(hT, fcw, fcb, labels, out);
}